// Round 12
// baseline (246.364 us; speedup 1.0000x reference)
//
#include <hip/hip_runtime.h>
#include <stdint.h>

typedef unsigned int u32;
typedef unsigned long long u64;
typedef unsigned short u16;
typedef unsigned char u8;

#define NQ 4096
#define NS 32768
#define ND 256
#define TOPK 32
#define CAP 256
#define CAP2 24
#define ZT 2.75f

#define QB 256                // queries per block (4 waves x 64 queries)
#define SB 64                 // rows per chunk (double R8 -> half the phases)
#define NSLICE 32
#define SLICE (NS / NSLICE)   // 1024
#define CH (SLICE / SB)       // 16 chunks per slice

typedef __attribute__((ext_vector_type(8))) __bf16 bf16x8;
typedef __attribute__((ext_vector_type(4))) float f32x4;

// workspace layout (bytes)
#define QB_OFF   (NS * ND * 2)              // 16 MiB bf16 source
#define TQ_OFF   (QB_OFF + NQ * ND * 2)     // + 2 MiB bf16 queries
#define C8_OFF   (TQ_OFF + NQ * 4)          // + 16 KB thresholds
#define CD_OFF   (C8_OFF + NQ * NSLICE)     // + 128 KB u8 counts [by][q]
// + NQ*NSLICE*CAP2*4 = 12.6 MB buckets -> ~30.1 MB total

__device__ __forceinline__ u16 f2bf(float x) {
  u32 u = __float_as_uint(x);
  u32 r = u + 0x7FFFu + ((u >> 16) & 1u);   // round-to-nearest-even
  return (u16)(r >> 16);
}

// ---------------- prep: fp32 source -> bf16 in ws ----------------
__global__ void k_prep_src(const float* __restrict__ src, uint4* __restrict__ dst) {
  int t = blockIdx.x * 256 + threadIdx.x;          // one thread = 8 elems
  const float4* s4 = (const float4*)src + (size_t)t * 2;
  float4 a = s4[0], b = s4[1];
  uint4 o;
  o.x = (u32)f2bf(a.x) | ((u32)f2bf(a.y) << 16);
  o.y = (u32)f2bf(a.z) | ((u32)f2bf(a.w) << 16);
  o.z = (u32)f2bf(b.x) | ((u32)f2bf(b.y) << 16);
  o.w = (u32)f2bf(b.z) | ((u32)f2bf(b.w) << 16);
  dst[t] = o;
}

// ---- prep: bf16 queries + per-query threshold ----
__global__ void k_prep_q(const float* __restrict__ qv, u16* __restrict__ qb,
                         float* __restrict__ tq) {
  int lane = threadIdx.x & 63, w = threadIdx.x >> 6;
  int q = blockIdx.x * 4 + w;                       // one wave per query row
  float4 v = *((const float4*)(qv + (size_t)q * ND) + lane);
  uint2 p;
  p.x = (u32)f2bf(v.x) | ((u32)f2bf(v.y) << 16);
  p.y = (u32)f2bf(v.z) | ((u32)f2bf(v.w) << 16);
  *((uint2*)(qb + (size_t)q * ND) + lane) = p;
  float s = v.x * v.x + v.y * v.y + v.z * v.z + v.w * v.w;
  #pragma unroll
  for (int o = 1; o < 64; o <<= 1) s += __shfl_xor(s, o, 64);
  if (lane == 0) tq[q] = ZT * sqrtf(s);
}

// -------- screen: wave = 64q x 64s per phase (SB=64 halves phase count) --------
// NOTE: launch bound stays (256,2): afrag alone is 128 VGPR; tighter bounds
// spill to scratch (R10: 871 MB FETCH, 3.3x slower). Unified VGPR+AGPR file
// means mt=4 kernels are hard-capped at 2 waves/SIMD regardless of grid.
__global__ __launch_bounds__(256, 2) void k_screen(
    const u16* __restrict__ qb, const u16* __restrict__ srcb,
    const float* __restrict__ tq, u8* __restrict__ cnt8, u32* __restrict__ cand2) {
  __shared__ __align__(16) u16 lds[2][SB * ND];     // 2 x 32 KB, XOR-swizzled octets
  __shared__ u32 bcnt[QB];                          // per-local-query candidate counts
  const int tid  = threadIdx.x;
  const int lane = tid & 63;
  const int w    = tid >> 6;                        // 0..3
  const int l15  = lane & 15, lhi = lane >> 4;

  // XCD-affine remap: XCD = id%8 owns slices [4*xcd, 4*xcd+4) -> L2-resident
  const int id   = blockIdx.x;
  const int xcd  = id & 7;
  const int rank = id >> 3;                         // 0..63
  const int by   = xcd * 4 + (rank >> 4);           // slice
  const int bx   = rank & 15;

  const int qbase = bx * QB + w * 64;               // wave owns 64 queries (4 M-tiles)
  const int sbase = by * SLICE;

  bcnt[tid] = 0u;

  // A-fragments (bf16 queries) + thresholds, persistent in registers
  bf16x8 afrag[4][8];
  float  thr[4][4];
  #pragma unroll
  for (int mt = 0; mt < 4; ++mt) {
    const u16* qp = qb + (size_t)(qbase + mt * 16 + l15) * ND;
    #pragma unroll
    for (int ks = 0; ks < 8; ++ks)
      afrag[mt][ks] = *((const bf16x8*)(qp + ks * 32 + lhi * 8));
    #pragma unroll
    for (int r = 0; r < 4; ++r) thr[mt][r] = tq[qbase + mt * 16 + lhi * 4 + r];
  }

  // per-thread pre-swizzled global octet offsets (u16 units); 8 instrs cover 32 KB
  int goff[8];
  #pragma unroll
  for (int i = 0; i < 8; ++i) {
    int slot = i * 256 + tid;                       // 2048 slots = 64 rows x 32 octets
    int row  = slot >> 5;
    int o    = (slot & 31) ^ (row & 7);
    goff[i]  = row * ND + o * 8;
  }

#define STAGE(b, c)                                                              \
  {                                                                              \
    const u16* sp_ = srcb + (size_t)(sbase + (c) * SB) * ND;                     \
    _Pragma("unroll")                                                            \
    for (int i_ = 0; i_ < 8; ++i_)                                               \
      __builtin_amdgcn_global_load_lds(                                          \
          (const __attribute__((address_space(1))) void*)(sp_ + goff[i_]),       \
          (__attribute__((address_space(3))) void*)(&lds[b][(i_ * 256 + tid) * 8]), \
          16, 0, 0);                                                             \
  }

#define COMPUTE(b, srow0)                                                        \
  {                                                                              \
    f32x4 acc[4][4];                                                             \
    _Pragma("unroll")                                                            \
    for (int mt = 0; mt < 4; ++mt)                                               \
      _Pragma("unroll")                                                          \
      for (int nt = 0; nt < 4; ++nt) acc[mt][nt] = (f32x4){0.f, 0.f, 0.f, 0.f};  \
    _Pragma("unroll")                                                            \
    for (int ks = 0; ks < 8; ++ks) {                                             \
      bf16x8 bfr[4];                                                             \
      _Pragma("unroll")                                                          \
      for (int nt = 0; nt < 4; ++nt) {                                           \
        int r_ = nt * 16 + l15;                                                  \
        int o_ = ks * 4 + lhi;                                                   \
        int slot_ = r_ * 32 + (o_ ^ (r_ & 7));                                   \
        bfr[nt] = *((const bf16x8*)(&lds[b][slot_ * 8]));                        \
      }                                                                          \
      _Pragma("unroll")                                                          \
      for (int mt = 0; mt < 4; ++mt)                                             \
        _Pragma("unroll")                                                        \
        for (int nt = 0; nt < 4; ++nt)                                           \
          acc[mt][nt] = __builtin_amdgcn_mfma_f32_16x16x32_bf16(                 \
              afrag[mt][ks], bfr[nt], acc[mt][nt], 0, 0, 0);                     \
    }                                                                            \
    _Pragma("unroll")                                                            \
    for (int mt = 0; mt < 4; ++mt)                                               \
      _Pragma("unroll")                                                          \
      for (int nt = 0; nt < 4; ++nt)                                             \
        _Pragma("unroll")                                                        \
        for (int r_ = 0; r_ < 4; ++r_) {                                         \
          float sc_ = acc[mt][nt][r_];                                           \
          if (sc_ > thr[mt][r_]) {                                               \
            int ql_ = w * 64 + mt * 16 + lhi * 4 + r_;                           \
            u32 off_ = atomicAdd(&bcnt[ql_], 1u);                                \
            if (off_ < CAP2)                                                     \
              cand2[(((size_t)(qbase + mt * 16 + lhi * 4 + r_)) * NSLICE + by) * CAP2 + off_] = \
                  ((u32)((srow0) + nt * 16 + l15) << 16) | (u32)f2bf(sc_);       \
          }                                                                      \
        }                                                                        \
  }

  // 2-phase prefetch pipeline (R4/R8-proven): stage(c+1) in flight during compute(c)
  STAGE(0, 0);
  __syncthreads();
  int cur = 0;
  for (int c = 0; c < CH - 1; ++c) {
    STAGE(cur ^ 1, c + 1);
    COMPUTE(cur, sbase + c * SB);
    __syncthreads();
    cur ^= 1;
  }
  COMPUTE(cur, sbase + (CH - 1) * SB);
#undef STAGE
#undef COMPUTE

  __syncthreads();
  // write per-(slice,q) counts -- transposed layout: contiguous per block
  {
    u32 c = bcnt[tid];
    cnt8[(size_t)by * NQ + bx * QB + tid] = (u8)(c < CAP2 ? c : CAP2);
  }
}

// ---------------- finish (R8-proven): gather buckets, LDS bitonic, exact re-score ----------------
__global__ __launch_bounds__(256) void k_finish(
    const float* __restrict__ qval, const float* __restrict__ sval,
    const float* __restrict__ sstate, const u8* __restrict__ cnt8,
    const u32* __restrict__ cand2, float* __restrict__ out) {
  const int q = blockIdx.x;
  const int tid = threadIdx.x;
  const int lane = tid & 63, w = tid >> 6;
  __shared__ u16  scnt[NSLICE];
  __shared__ u16  soff[NSLICE];
  __shared__ u32  skey[CAP];
  __shared__ u32  sidxl[CAP];
  __shared__ float sexact[64];
  __shared__ u32  ssrc[64];
  __shared__ float fw[TOPK];
  __shared__ u32  fi[TOPK];

  if (tid < NSLICE) scnt[tid] = cnt8[(size_t)tid * NQ + q];
  skey[tid] = 0u;                      // pad key = 0 (real keys are > 0)
  __syncthreads();
  if (tid == 0) {
    u32 a = 0;
    #pragma unroll
    for (int s = 0; s < NSLICE; ++s) { soff[s] = (u16)a; a += scnt[s]; }
  }
  __syncthreads();

  // gather bucket entries -> compact list; key = (bf16score << 8) | pos
  {
    int s = tid >> 3, j0 = tid & 7;
    #pragma unroll
    for (int rep = 0; rep < 3; ++rep) {
      int j = j0 + rep * 8;
      if (j < (int)scnt[s]) {
        int p = (int)soff[s] + j;
        if (p < CAP) {
          u32 ent = cand2[((size_t)q * NSLICE + s) * CAP2 + j];
          skey[p]  = ((ent & 0xFFFFu) << 8) | (u32)p;
          sidxl[p] = ent >> 16;
        }
      }
    }
  }
  __syncthreads();

  // bitonic sort 256 u32 keys descending (LDS)
  for (int k = 2; k <= 256; k <<= 1) {
    for (int j = k >> 1; j > 0; j >>= 1) {
      int p = tid ^ j;
      u32 a = skey[tid], b = skey[p];
      bool keepMax = ((tid < p) == ((tid & k) == 0));
      u32 r = keepMax ? (a > b ? a : b) : (a > b ? b : a);
      __syncthreads();
      skey[tid] = r;
      __syncthreads();
    }
  }

  // exact fp32 re-score of approx-top-64: 4 rows in flight per wave, 16 lanes/row
  const int l16 = lane & 15, sub = lane >> 4;
  float4 qf[4];
  #pragma unroll
  for (int j = 0; j < 4; ++j)
    qf[j] = *((const float4*)(qval + (size_t)q * ND) + l16 * 4 + j);
  #pragma unroll
  for (int p = 0; p < 4; ++p) {
    int e = w * 16 + p * 4 + sub;
    u32 key = skey[e];
    u32 si = sidxl[key & 0xFFu];
    float dp = 0.f;
    if (key) {
      const float4* vp = (const float4*)(sval + (size_t)si * ND) + l16 * 4;
      #pragma unroll
      for (int j = 0; j < 4; ++j) {
        float4 v = vp[j];
        dp += qf[j].x * v.x + qf[j].y * v.y + qf[j].z * v.z + qf[j].w * v.w;
      }
    }
    #pragma unroll
    for (int o = 1; o < 16; o <<= 1) dp += __shfl_xor(dp, o, 64);
    if (l16 == 0) { sexact[e] = key ? dp : -3.0e38f; ssrc[e] = si; }
  }
  __syncthreads();

  // wave 0: exact top-32 of the 64 (desc, tie -> lower idx), weights + delta_state
  if (w == 0) {
    float sc = sexact[lane];
    u32 si  = ssrc[lane];
    u32 kb  = __float_as_uint(sc);
    kb = kb ^ (u32)(((int)kb >> 31) | 0x80000000);
    u64 kk = ((u64)kb << 32) | (u32)(~si);
    #pragma unroll
    for (int k = 2; k <= 64; k <<= 1) {
      #pragma unroll
      for (int j = k >> 1; j > 0; j >>= 1) {
        u64 o = __shfl_xor(kk, j, 64);
        bool keepMax = (((lane & j) == 0) == ((lane & k) == 0));
        kk = keepMax ? (kk > o ? kk : o) : (kk > o ? o : kk);
      }
    }
    u32 si2 = ~((u32)kk);
    u32 kb2 = (u32)(kk >> 32);
    u32 fb  = (kb2 & 0x80000000u) ? (kb2 ^ 0x80000000u) : ~kb2;
    float s = __uint_as_float(fb);
    bool ok = (lane < TOPK) && (s > -1.0e38f);
    float edge = ok ? (s / (1.f + fabsf(s))) : 0.f;
    float contrib = ok ? edge * sstate[si2] : 0.f;
    if (lane < TOPK) { fw[lane] = edge; fi[lane] = ok ? si2 : 0u; }
    #pragma unroll
    for (int o = 1; o < 64; o <<= 1) contrib += __shfl_xor(contrib, o, 64);
    if (lane == 0) out[q] = contrib;
  }
  __syncthreads();

  // delta_val: thread tid owns dimension d = tid, coalesced fp32 gathers
  float acc = 0.f;
  #pragma unroll 8
  for (int k = 0; k < TOPK; ++k)
    acc += fw[k] * sval[(size_t)fi[k] * ND + tid];
  out[NQ + (size_t)q * ND + tid] = acc;
}

extern "C" void kernel_launch(void* const* d_in, const int* in_sizes, int n_in,
                              void* d_out, int out_size, void* d_ws, size_t ws_size,
                              hipStream_t stream) {
  const float* qval   = (const float*)d_in[0];
  const float* sval   = (const float*)d_in[1];
  const float* sstate = (const float*)d_in[2];
  float* out = (float*)d_out;
  char*  ws  = (char*)d_ws;
  u16*   srcb  = (u16*)ws;
  u16*   qbuf  = (u16*)(ws + QB_OFF);
  float* tq    = (float*)(ws + TQ_OFF);
  u8*    cnt8  = (u8*)(ws + C8_OFF);
  u32*   cand2 = (u32*)(ws + CD_OFF);

  k_prep_src<<<(NS * ND / 8) / 256, 256, 0, stream>>>(sval, (uint4*)srcb);
  k_prep_q<<<NQ / 4, 256, 0, stream>>>(qval, qbuf, tq);
  k_screen<<<(NQ / QB) * NSLICE, 256, 0, stream>>>(qbuf, srcb, tq, cnt8, cand2);
  k_finish<<<NQ, 256, 0, stream>>>(qval, sval, sstate, cnt8, cand2, out);
}

// Round 13
// 151.600 us; speedup vs baseline: 1.6251x; 1.6251x over previous
//
#include <hip/hip_runtime.h>
#include <stdint.h>

typedef unsigned int u32;
typedef unsigned long long u64;
typedef unsigned short u16;
typedef unsigned char u8;

#define NQ 4096
#define NS 32768
#define ND 256
#define TOPK 32
#define CAP 256
#define CAP2 24
#define ZT 2.75f

#define QB 256                // queries per block (4 waves x 64 queries)
#define SB 32
#define NSLICE 32
#define SLICE (NS / NSLICE)   // 1024
#define CH (SLICE / SB)       // 32 chunks per slice

typedef __attribute__((ext_vector_type(8))) __bf16 bf16x8;
typedef __attribute__((ext_vector_type(4))) float f32x4;

// workspace layout (bytes)
#define QB_OFF   (NS * ND * 2)              // 16 MiB bf16 source
#define TQ_OFF   (QB_OFF + NQ * ND * 2)     // + 2 MiB bf16 queries
#define C8_OFF   (TQ_OFF + NQ * 4)          // + 16 KB thresholds
#define CD_OFF   (C8_OFF + NQ * NSLICE)     // + 128 KB u8 counts [by][q]
// + NQ*NSLICE*CAP2*4 = 12.6 MB buckets -> ~30.1 MB total

__device__ __forceinline__ u16 f2bf(float x) {
  u32 u = __float_as_uint(x);
  u32 r = u + 0x7FFFu + ((u >> 16) & 1u);   // round-to-nearest-even
  return (u16)(r >> 16);
}

// ---------------- prep: fp32 source -> bf16 in ws ----------------
__global__ void k_prep_src(const float* __restrict__ src, uint4* __restrict__ dst) {
  int t = blockIdx.x * 256 + threadIdx.x;          // one thread = 8 elems
  const float4* s4 = (const float4*)src + (size_t)t * 2;
  float4 a = s4[0], b = s4[1];
  uint4 o;
  o.x = (u32)f2bf(a.x) | ((u32)f2bf(a.y) << 16);
  o.y = (u32)f2bf(a.z) | ((u32)f2bf(a.w) << 16);
  o.z = (u32)f2bf(b.x) | ((u32)f2bf(b.y) << 16);
  o.w = (u32)f2bf(b.z) | ((u32)f2bf(b.w) << 16);
  dst[t] = o;
}

// ---- prep: bf16 queries + per-query threshold ----
__global__ void k_prep_q(const float* __restrict__ qv, u16* __restrict__ qb,
                         float* __restrict__ tq) {
  int lane = threadIdx.x & 63, w = threadIdx.x >> 6;
  int q = blockIdx.x * 4 + w;                       // one wave per query row
  float4 v = *((const float4*)(qv + (size_t)q * ND) + lane);
  uint2 p;
  p.x = (u32)f2bf(v.x) | ((u32)f2bf(v.y) << 16);
  p.y = (u32)f2bf(v.z) | ((u32)f2bf(v.w) << 16);
  *((uint2*)(qb + (size_t)q * ND) + lane) = p;
  float s = v.x * v.x + v.y * v.y + v.z * v.z + v.w * v.w;
  #pragma unroll
  for (int o = 1; o < 64; o <<= 1) s += __shfl_xor(s, o, 64);
  if (lane == 0) tq[q] = ZT * sqrtf(s);
}

// -------- screen (R8-proven, frozen): bf16 MFMA, wave = 64q x 32s --------
// NOTE: launch bound MUST stay (256,2): the kernel needs 128 VGPR (afrag alone
// is 128); tighter bounds spill afrag to scratch (R10: 871 MB FETCH, 3.3x
// slower; R12: acc[4][4] spill, 2x slower). Structural perturbations
// (R6/R7/R9/R11/R12) all regressed -- this config is a sharp local optimum.
__global__ __launch_bounds__(256, 2) void k_screen(
    const u16* __restrict__ qb, const u16* __restrict__ srcb,
    const float* __restrict__ tq, u8* __restrict__ cnt8, u32* __restrict__ cand2) {
  __shared__ __align__(16) u16 lds[2][SB * ND];     // 2 x 16 KB, XOR-swizzled octets
  __shared__ u32 bcnt[QB];                          // per-local-query candidate counts
  const int tid  = threadIdx.x;
  const int lane = tid & 63;
  const int w    = tid >> 6;                        // 0..3
  const int l15  = lane & 15, lhi = lane >> 4;

  // XCD-affine remap: XCD = id%8 owns slices [4*xcd, 4*xcd+4) -> L2-resident
  const int id   = blockIdx.x;
  const int xcd  = id & 7;
  const int rank = id >> 3;                         // 0..63
  const int by   = xcd * 4 + (rank >> 4);           // slice
  const int bx   = rank & 15;

  const int qbase = bx * QB + w * 64;               // wave owns 64 queries (4 M-tiles)
  const int sbase = by * SLICE;

  bcnt[tid] = 0u;

  // A-fragments (bf16 queries) + thresholds, persistent in registers
  bf16x8 afrag[4][8];
  float  thr[4][4];
  #pragma unroll
  for (int mt = 0; mt < 4; ++mt) {
    const u16* qp = qb + (size_t)(qbase + mt * 16 + l15) * ND;
    #pragma unroll
    for (int ks = 0; ks < 8; ++ks)
      afrag[mt][ks] = *((const bf16x8*)(qp + ks * 32 + lhi * 8));
    #pragma unroll
    for (int r = 0; r < 4; ++r) thr[mt][r] = tq[qbase + mt * 16 + lhi * 4 + r];
  }

  // per-thread pre-swizzled global octet offsets (u16 units); 4 instrs cover 16 KB
  int goff[4];
  #pragma unroll
  for (int i = 0; i < 4; ++i) {
    int slot = i * 256 + tid;
    int row  = slot >> 5;
    int o    = (slot & 31) ^ (row & 7);
    goff[i]  = row * ND + o * 8;
  }

#define STAGE(b, c)                                                              \
  {                                                                              \
    const u16* sp_ = srcb + (size_t)(sbase + (c) * SB) * ND;                     \
    _Pragma("unroll")                                                            \
    for (int i_ = 0; i_ < 4; ++i_)                                               \
      __builtin_amdgcn_global_load_lds(                                          \
          (const __attribute__((address_space(1))) void*)(sp_ + goff[i_]),       \
          (__attribute__((address_space(3))) void*)(&lds[b][(i_ * 256 + tid) * 8]), \
          16, 0, 0);                                                             \
  }

#define COMPUTE(b, srow0)                                                        \
  {                                                                              \
    f32x4 acc[4][2];                                                             \
    _Pragma("unroll")                                                            \
    for (int mt = 0; mt < 4; ++mt)                                               \
      _Pragma("unroll")                                                          \
      for (int nt = 0; nt < 2; ++nt) acc[mt][nt] = (f32x4){0.f, 0.f, 0.f, 0.f};  \
    _Pragma("unroll")                                                            \
    for (int ks = 0; ks < 8; ++ks) {                                             \
      bf16x8 bfr[2];                                                             \
      _Pragma("unroll")                                                          \
      for (int nt = 0; nt < 2; ++nt) {                                           \
        int r_ = nt * 16 + l15;                                                  \
        int o_ = ks * 4 + lhi;                                                   \
        int slot_ = r_ * 32 + (o_ ^ (r_ & 7));                                   \
        bfr[nt] = *((const bf16x8*)(&lds[b][slot_ * 8]));                        \
      }                                                                          \
      _Pragma("unroll")                                                          \
      for (int mt = 0; mt < 4; ++mt)                                             \
        _Pragma("unroll")                                                        \
        for (int nt = 0; nt < 2; ++nt)                                           \
          acc[mt][nt] = __builtin_amdgcn_mfma_f32_16x16x32_bf16(                 \
              afrag[mt][ks], bfr[nt], acc[mt][nt], 0, 0, 0);                     \
    }                                                                            \
    _Pragma("unroll")                                                            \
    for (int mt = 0; mt < 4; ++mt)                                               \
      _Pragma("unroll")                                                          \
      for (int nt = 0; nt < 2; ++nt)                                             \
        _Pragma("unroll")                                                        \
        for (int r_ = 0; r_ < 4; ++r_) {                                         \
          float sc_ = acc[mt][nt][r_];                                           \
          if (sc_ > thr[mt][r_]) {                                               \
            int ql_ = w * 64 + mt * 16 + lhi * 4 + r_;                           \
            u32 off_ = atomicAdd(&bcnt[ql_], 1u);                                \
            if (off_ < CAP2)                                                     \
              cand2[(((size_t)(qbase + mt * 16 + lhi * 4 + r_)) * NSLICE + by) * CAP2 + off_] = \
                  ((u32)((srow0) + nt * 16 + l15) << 16) | (u32)f2bf(sc_);       \
          }                                                                      \
        }                                                                        \
  }

  // 2-phase prefetch pipeline (R4/R8-proven): stage(c+1) in flight during compute(c)
  STAGE(0, 0);
  __syncthreads();
  int cur = 0;
  for (int c = 0; c < CH - 1; ++c) {
    STAGE(cur ^ 1, c + 1);
    COMPUTE(cur, sbase + c * SB);
    __syncthreads();
    cur ^= 1;
  }
  COMPUTE(cur, sbase + (CH - 1) * SB);
#undef STAGE
#undef COMPUTE

  __syncthreads();
  // write per-(slice,q) counts -- transposed layout: contiguous per block
  {
    u32 c = bcnt[tid];
    cnt8[(size_t)by * NQ + bx * QB + tid] = (u8)(c < CAP2 ? c : CAP2);
  }
}

// ------- finish: gather, HYBRID bitonic (shfl intra-wave, LDS only j>=64), rescore -------
__global__ __launch_bounds__(256) void k_finish(
    const float* __restrict__ qval, const float* __restrict__ sval,
    const float* __restrict__ sstate, const u8* __restrict__ cnt8,
    const u32* __restrict__ cand2, float* __restrict__ out) {
  const int q = blockIdx.x;
  const int tid = threadIdx.x;
  const int lane = tid & 63, w = tid >> 6;
  __shared__ u16  scnt[NSLICE];
  __shared__ u16  soff[NSLICE];
  __shared__ u32  skey[CAP];
  __shared__ u32  sidxl[CAP];
  __shared__ float sexact[64];
  __shared__ u32  ssrc[64];
  __shared__ float fw[TOPK];
  __shared__ u32  fi[TOPK];

  if (tid < NSLICE) scnt[tid] = cnt8[(size_t)tid * NQ + q];
  skey[tid] = 0u;                      // pad key = 0 (real keys are > 0)
  __syncthreads();
  if (tid == 0) {
    u32 a = 0;
    #pragma unroll
    for (int s = 0; s < NSLICE; ++s) { soff[s] = (u16)a; a += scnt[s]; }
  }
  __syncthreads();

  // gather bucket entries -> compact list; key = (bf16score << 8) | pos
  {
    int s = tid >> 3, j0 = tid & 7;
    #pragma unroll
    for (int rep = 0; rep < 3; ++rep) {
      int j = j0 + rep * 8;
      if (j < (int)scnt[s]) {
        int p = (int)soff[s] + j;
        if (p < CAP) {
          u32 ent = cand2[((size_t)q * NSLICE + s) * CAP2 + j];
          skey[p]  = ((ent & 0xFFFFu) << 8) | (u32)p;
          sidxl[p] = ent >> 16;
        }
      }
    }
  }
  __syncthreads();

  // hybrid bitonic sort 256 keys descending, element i = tid = w*64+lane.
  // Identical comparator network to the LDS version (same predicate,
  // ((tid&j)==0)==((tid&k)==0), partner tid^j) -- but j<64 steps swap via
  // intra-wave shfl (no barrier). Only j in {64,128} go through LDS:
  // 3 LDS steps (6 barriers) instead of 36 (72 barriers).
  {
    u32 key = skey[tid];
    #pragma unroll
    for (int k = 2; k <= 256; k <<= 1) {
      #pragma unroll
      for (int j = k >> 1; j > 0; j >>= 1) {
        u32 o;
        if (j >= 64) {
          skey[tid] = key;
          __syncthreads();
          o = skey[tid ^ j];
          __syncthreads();
        } else {
          o = __shfl_xor(key, j, 64);
        }
        bool keepMax = ((tid & j) == 0) == ((tid & k) == 0);
        key = keepMax ? (key > o ? key : o) : (key > o ? o : key);
      }
    }
    skey[tid] = key;
  }
  __syncthreads();

  // exact fp32 re-score of approx-top-64: 4 rows in flight per wave, 16 lanes/row
  const int l16 = lane & 15, sub = lane >> 4;
  float4 qf[4];
  #pragma unroll
  for (int j = 0; j < 4; ++j)
    qf[j] = *((const float4*)(qval + (size_t)q * ND) + l16 * 4 + j);
  #pragma unroll
  for (int p = 0; p < 4; ++p) {
    int e = w * 16 + p * 4 + sub;
    u32 key = skey[e];
    u32 si = sidxl[key & 0xFFu];
    float dp = 0.f;
    if (key) {
      const float4* vp = (const float4*)(sval + (size_t)si * ND) + l16 * 4;
      #pragma unroll
      for (int j = 0; j < 4; ++j) {
        float4 v = vp[j];
        dp += qf[j].x * v.x + qf[j].y * v.y + qf[j].z * v.z + qf[j].w * v.w;
      }
    }
    #pragma unroll
    for (int o = 1; o < 16; o <<= 1) dp += __shfl_xor(dp, o, 64);
    if (l16 == 0) { sexact[e] = key ? dp : -3.0e38f; ssrc[e] = si; }
  }
  __syncthreads();

  // wave 0: exact top-32 of the 64 (desc, tie -> lower idx), weights + delta_state
  if (w == 0) {
    float sc = sexact[lane];
    u32 si  = ssrc[lane];
    u32 kb  = __float_as_uint(sc);
    kb = kb ^ (u32)(((int)kb >> 31) | 0x80000000);
    u64 kk = ((u64)kb << 32) | (u32)(~si);
    #pragma unroll
    for (int k = 2; k <= 64; k <<= 1) {
      #pragma unroll
      for (int j = k >> 1; j > 0; j >>= 1) {
        u64 o = __shfl_xor(kk, j, 64);
        bool keepMax = (((lane & j) == 0) == ((lane & k) == 0));
        kk = keepMax ? (kk > o ? kk : o) : (kk > o ? o : kk);
      }
    }
    u32 si2 = ~((u32)kk);
    u32 kb2 = (u32)(kk >> 32);
    u32 fb  = (kb2 & 0x80000000u) ? (kb2 ^ 0x80000000u) : ~kb2;
    float s = __uint_as_float(fb);
    bool ok = (lane < TOPK) && (s > -1.0e38f);
    float edge = ok ? (s / (1.f + fabsf(s))) : 0.f;
    float contrib = ok ? edge * sstate[si2] : 0.f;
    if (lane < TOPK) { fw[lane] = edge; fi[lane] = ok ? si2 : 0u; }
    #pragma unroll
    for (int o = 1; o < 64; o <<= 1) contrib += __shfl_xor(contrib, o, 64);
    if (lane == 0) out[q] = contrib;
  }
  __syncthreads();

  // delta_val: thread tid owns dimension d = tid, coalesced fp32 gathers
  float acc = 0.f;
  #pragma unroll 8
  for (int k = 0; k < TOPK; ++k)
    acc += fw[k] * sval[(size_t)fi[k] * ND + tid];
  out[NQ + (size_t)q * ND + tid] = acc;
}

extern "C" void kernel_launch(void* const* d_in, const int* in_sizes, int n_in,
                              void* d_out, int out_size, void* d_ws, size_t ws_size,
                              hipStream_t stream) {
  const float* qval   = (const float*)d_in[0];
  const float* sval   = (const float*)d_in[1];
  const float* sstate = (const float*)d_in[2];
  float* out = (float*)d_out;
  char*  ws  = (char*)d_ws;
  u16*   srcb  = (u16*)ws;
  u16*   qbuf  = (u16*)(ws + QB_OFF);
  float* tq    = (float*)(ws + TQ_OFF);
  u8*    cnt8  = (u8*)(ws + C8_OFF);
  u32*   cand2 = (u32*)(ws + CD_OFF);

  k_prep_src<<<(NS * ND / 8) / 256, 256, 0, stream>>>(sval, (uint4*)srcb);
  k_prep_q<<<NQ / 4, 256, 0, stream>>>(qval, qbuf, tq);
  k_screen<<<(NQ / QB) * NSLICE, 256, 0, stream>>>(qbuf, srcb, tq, cnt8, cand2);
  k_finish<<<NQ, 256, 0, stream>>>(qval, sval, sstate, cnt8, cand2, out);
}